// Round 8
// baseline (182.626 us; speedup 1.0000x reference)
//
#include <hip/hip_runtime.h>

#define CHVOL (128*128*128)

// 9 stats: [S_-2, S_-1, S_0(count), S_1, S_2, S_3, S_4, S_5, T=sum x*ln x]
// Branchless: cndmask + fma, no divergent branch.
__device__ __forceinline__ void accum9(float* a, float x) {
    bool nz = (x != 0.0f);
    float u = nz ? __builtin_amdgcn_rcpf(x) : 0.0f;
    float l = nz ? __logf(x) : 0.0f;
    float x2 = x * x;
    float x4 = x2 * x2;
    a[0] = fmaf(u, u, a[0]);
    a[1] += u;
    a[2] += nz ? 1.0f : 0.0f;
    a[3] += x;
    a[4] += x2;
    a[5] = fmaf(x2, x, a[5]);
    a[6] += x4;
    a[7] = fmaf(x4, x, a[7]);
    a[8] = fmaf(x, l, a[8]);
}

// NW-wave block reduce of NS stats; per-wave partials land in red[w*NS + s].
template<int NS, int NW>
__device__ __forceinline__ void block_reduce(float* acc, float* red, int t) {
    #pragma unroll
    for (int s = 0; s < NS; ++s) {
        float v = acc[s];
        v += __shfl_down(v, 32, 64);
        v += __shfl_down(v, 16, 64);
        v += __shfl_down(v, 8, 64);
        v += __shfl_down(v, 4, 64);
        v += __shfl_down(v, 2, 64);
        v += __shfl_down(v, 1, 64);
        if ((t & 63) == 0) red[(t >> 6) * NS + s] = v;
    }
    __syncthreads();
}

// Block = one 32x32x32 region -> ALL six pyramid levels in-block.
// Thread (xq 8, y 32 via yl+8*(wv&3), zb 2): owns 4x * 1y * 16z = 16 float4.
// L1: x-pairs in float4, y-pair lane^8, z-pairs in-thread.
// L2: x-quad in float4, y-quad +lane^16, z-quad in-thread. (x4 replicated)
// L3: +lane^1 (x-oct), +lane^32 (y-oct), z-oct in-thread. (x16 replicated)
// L4/L5: via 64-entry LDS map of L3 cells, finished serially by t==0.
// Output: 54 stats/block -> part[(ch*54 + j)*64 + blk]  (83 KB total).
__global__ __launch_bounds__(512, 4) void k_main(const float* __restrict__ img,
                                                 float* __restrict__ part) {
    __shared__ float m3[64];          // L3 cells [z3 4][y3 4][x3 4]
    __shared__ float red[36 * 8];

    const int t  = threadIdx.x;
    const int l  = t & 63, wv = t >> 6;       // 8 waves
    const int xq = t & 7;                     // float4 column (x = 4*xq)
    const int yl = (t >> 3) & 7;
    const int y  = yl + 8 * (wv & 3);         // y in [0,32)
    const int zb = wv >> 2;                   // z base = 16*zb
    const int blk = blockIdx.x;               // 0..63
    const int ch  = blockIdx.y;               // 0..5
    const int bx = blk & 3, by = (blk >> 2) & 3, bz = blk >> 4;

    const float* tb = img + (size_t)ch * CHVOL
                    + (size_t)(bz * 32 + zb * 16) * 16384
                    + (by * 32 + y) * 128 + bx * 32 + xq * 4;

    float acc[36];
    #pragma unroll
    for (int j = 0; j < 36; ++j) acc[j] = 0.0f;

    // Prefetch all 16 z-slices (790 KB in flight grid-wide).
    float4 v[16];
    #pragma unroll
    for (int i = 0; i < 16; ++i) v[i] = *(const float4*)(tb + i * 16384);

    float oct0, oct1;
    #pragma unroll
    for (int h = 0; h < 2; ++h) {             // two z-octs per thread
        float q0 = 0.0f, q1 = 0.0f;           // L2 z-quad partials
        float ca = 0.0f, cb = 0.0f;
        #pragma unroll
        for (int i = 0; i < 8; ++i) {
            float4 u = v[h * 8 + i];
            accum9(acc, u.x); accum9(acc, u.y); accum9(acc, u.z); accum9(acc, u.w);
            float a = u.x + u.y, b = u.z + u.w;      // x-paired halves
            a += __shfl_xor(a, 8, 64);               // y-pair (yl^1)
            b += __shfl_xor(b, 8, 64);
            if ((i & 1) == 0) { ca = a; cb = b; }
            else {
                float A = ca + a, B = cb + b;        // L1 cells, replicated x2
                accum9(acc + 9, A); accum9(acc + 9, B);
                float s = A + B;
                if (i < 4) q0 += s; else q1 += s;
            }
        }
        q0 += __shfl_xor(q0, 16, 64);                // y-quad -> L2, replicated x4
        q1 += __shfl_xor(q1, 16, 64);
        accum9(acc + 18, q0); accum9(acc + 18, q1);
        float o = q0 + q1;                           // (4x,4y,8z)
        o += __shfl_xor(o, 1, 64);                   // x-oct
        o += __shfl_xor(o, 32, 64);                  // y-oct -> L3, replicated x16
        accum9(acc + 27, o);
        if (h == 0) oct0 = o; else oct1 = o;
    }
    #pragma unroll
    for (int j = 9;  j < 18; ++j) acc[j] *= 0.5f;    // undo x2 replication
    #pragma unroll
    for (int j = 18; j < 27; ++j) acc[j] *= 0.25f;   // x4
    #pragma unroll
    for (int j = 27; j < 36; ++j) acc[j] *= 0.0625f; // x16

    if ((l & 57) == 0) {              // lanes 0,2,4,6: one writer per 16-lane group
        int x3 = (l >> 1) & 3, y3 = wv & 3;
        m3[(zb * 2 + 0) * 16 + y3 * 4 + x3] = oct0;
        m3[(zb * 2 + 1) * 16 + y3 * 4 + x3] = oct1;
    }
    __syncthreads();

    // L4 (2x2x2 of L3) + L5, serial on t==0 (~200 cycles), stats stored direct.
    if (t == 0) {
        float a45[18];
        #pragma unroll
        for (int q = 0; q < 18; ++q) a45[q] = 0.0f;
        float s5 = 0.0f;
        #pragma unroll
        for (int c = 0; c < 8; ++c) {
            int x4 = c & 1, y4 = (c >> 1) & 1, z4 = c >> 2;
            float s = 0.0f;
            #pragma unroll
            for (int dz = 0; dz < 2; ++dz)
                #pragma unroll
                for (int dy = 0; dy < 2; ++dy)
                    #pragma unroll
                    for (int dx = 0; dx < 2; ++dx)
                        s += m3[(2 * z4 + dz) * 16 + (2 * y4 + dy) * 4 + (2 * x4 + dx)];
            accum9(a45, s);
            s5 += s;
        }
        accum9(a45 + 9, s5);
        #pragma unroll
        for (int q = 0; q < 18; ++q)
            part[((size_t)ch * 54 + 36 + q) * 64 + blk] = a45[q];
    }

    block_reduce<36, 8>(acc, red, t);
    if (t < 36) {
        float s = 0.0f;
        #pragma unroll
        for (int w2 = 0; w2 < 8; ++w2) s += red[w2 * 36 + t];
        part[((size_t)ch * 54 + t) * 64 + blk] = s;
    }
}

// One wave per channel: reduce 64 block-partials per stat, then the finale.
__global__ __launch_bounds__(64) void k_fin(const float* __restrict__ part,
                                            const int* __restrict__ bounds,
                                            float* __restrict__ out) {
    __shared__ float sst[54];
    const int t  = threadIdx.x;       // 0..63 = block index within channel
    const int ch = blockIdx.x;

    #pragma unroll
    for (int j = 0; j < 54; ++j) {
        float v = part[((size_t)ch * 54 + j) * 64 + t];
        v += __shfl_down(v, 32, 64);
        v += __shfl_down(v, 16, 64);
        v += __shfl_down(v, 8, 64);
        v += __shfl_down(v, 4, 64);
        v += __shfl_down(v, 2, 64);
        v += __shfl_down(v, 1, 64);
        if (t == 0) sst[j] = v;
    }
    __syncthreads();

    // ---- finale: least-squares slope, double precision, 8 outputs ----
    if (t < 8) {
        int k = bounds[t];
        const double LN2 = 0.6931471805599453094;
        double b  = (double)sst[3];          // S_1 at level 0 == total sum
        double lb = log(b);
        double num = 0.0;
        #pragma unroll
        for (int s = 0; s < 6; ++s) {
            const float* st = sst + s * 9;
            double p;
            if (k == 1) p = ((double)st[8] - lb * (double)st[3]) / b;
            else        p = log((double)st[k + 2]) - (double)k * lb;
            num += (6.0 * s - 15.0) * LN2 * p;   // n*q_s - qs
        }
        double den = 105.0 * LN2 * LN2;          // n*q2s - qs^2
        double aa  = (k == 1) ? 1.0 : 1.0 / (double)(k - 1);
        out[ch * 8 + t] = (float)(aa * num / den);
    }
}

extern "C" void kernel_launch(void* const* d_in, const int* in_sizes, int n_in,
                              void* d_out, int out_size, void* d_ws, size_t ws_size,
                              hipStream_t stream) {
    const float* img    = (const float*)d_in[0];
    const int*   bounds = (const int*)d_in[1];
    float*       out    = (float*)d_out;
    float*       ws     = (float*)d_ws;

    // ws layout (floats): part[6*54*64 = 20736] @0. No l3map, no flags.
    float* part = ws;

    k_main<<<dim3(64, 6), 512, 0, stream>>>(img, part);
    k_fin<<<6, 64, 0, stream>>>(part, bounds, out);
}

// Round 9
// 138.258 us; speedup vs baseline: 1.3209x; 1.3209x over previous
//
#include <hip/hip_runtime.h>

#define CHVOL (128*128*128)

// 9 stats: [S_-2, S_-1, S_0(count), S_1, S_2, S_3, S_4, S_5, T=sum x*ln x]
// Branchless: cndmask + fma, no divergent branch.
__device__ __forceinline__ void accum9(float* a, float x) {
    bool nz = (x != 0.0f);
    float u = nz ? __builtin_amdgcn_rcpf(x) : 0.0f;
    float l = nz ? __logf(x) : 0.0f;
    float x2 = x * x;
    float x4 = x2 * x2;
    a[0] = fmaf(u, u, a[0]);
    a[1] += u;
    a[2] += nz ? 1.0f : 0.0f;
    a[3] += x;
    a[4] += x2;
    a[5] = fmaf(x2, x, a[5]);
    a[6] += x4;
    a[7] = fmaf(x4, x, a[7]);
    a[8] = fmaf(x, l, a[8]);
}

// 8-wave block reduce of NS stats; per-wave partials land in red[w*NS + s].
template<int NS>
__device__ __forceinline__ void block_reduce(float* acc, float* red, int t) {
    #pragma unroll
    for (int s = 0; s < NS; ++s) {
        float v = acc[s];
        v += __shfl_down(v, 32, 64);
        v += __shfl_down(v, 16, 64);
        v += __shfl_down(v, 8, 64);
        v += __shfl_down(v, 4, 64);
        v += __shfl_down(v, 2, 64);
        v += __shfl_down(v, 1, 64);
        if ((t & 63) == 0) red[(t >> 6) * NS + s] = v;
    }
    __syncthreads();
}

// Block = one 32x32x32 region -> ALL six pyramid levels in-block.
// Thread (xq 8, y 32 via yl+8*(wv&3), zb 2): owns 4x * 1y * 16z.
// Prefetch is TWO sequential batches of 8 float4 (live set ~100 VGPR, no
// spill; round 8's v[16] spilled at the 64-reg allocation -> 80 MB scratch).
// L1: x-pairs in float4, y-pair lane^8, z-pairs in-thread.
// L2: x-quad in float4, y-quad +lane^16, z-quad in-thread. (x4 replicated)
// L3: +lane^1 (x-oct), +lane^32 (y-oct), z-oct in-thread. (x16 replicated)
// L4/L5: via 64-entry LDS map of L3 cells, finished serially by t==0.
// Output: 54 stats/block -> part[(ch*54 + j)*64 + blk]  (83 KB total).
__global__ __launch_bounds__(512, 2) void k_main(const float* __restrict__ img,
                                                 float* __restrict__ part) {
    __shared__ float m3[64];          // L3 cells [z3 4][y3 4][x3 4]
    __shared__ float red[36 * 8];

    const int t  = threadIdx.x;
    const int l  = t & 63, wv = t >> 6;       // 8 waves
    const int xq = t & 7;                     // float4 column (x = 4*xq)
    const int yl = (t >> 3) & 7;
    const int y  = yl + 8 * (wv & 3);         // y in [0,32)
    const int zb = wv >> 2;                   // z base = 16*zb
    const int blk = blockIdx.x;               // 0..63
    const int ch  = blockIdx.y;               // 0..5
    const int bx = blk & 3, by = (blk >> 2) & 3, bz = blk >> 4;

    const float* tb = img + (size_t)ch * CHVOL
                    + (size_t)(bz * 32 + zb * 16) * 16384
                    + (by * 32 + y) * 128 + bx * 32 + xq * 4;

    float acc[36];
    #pragma unroll
    for (int j = 0; j < 36; ++j) acc[j] = 0.0f;

    float oct0, oct1;
    #pragma unroll
    for (int h = 0; h < 2; ++h) {             // two z-octs per thread
        // Batch prefetch: 8 float4 in flight, separate live range per half.
        float4 v8[8];
        #pragma unroll
        for (int i = 0; i < 8; ++i) v8[i] = *(const float4*)(tb + (h * 8 + i) * 16384);

        float q0 = 0.0f, q1 = 0.0f;           // L2 z-quad partials
        float ca = 0.0f, cb = 0.0f;
        #pragma unroll
        for (int i = 0; i < 8; ++i) {
            float4 u = v8[i];
            accum9(acc, u.x); accum9(acc, u.y); accum9(acc, u.z); accum9(acc, u.w);
            float a = u.x + u.y, b = u.z + u.w;      // x-paired halves
            a += __shfl_xor(a, 8, 64);               // y-pair (yl^1)
            b += __shfl_xor(b, 8, 64);
            if ((i & 1) == 0) { ca = a; cb = b; }
            else {
                float A = ca + a, B = cb + b;        // L1 cells, replicated x2
                accum9(acc + 9, A); accum9(acc + 9, B);
                float s = A + B;
                if (i < 4) q0 += s; else q1 += s;
            }
        }
        q0 += __shfl_xor(q0, 16, 64);                // y-quad -> L2, replicated x4
        q1 += __shfl_xor(q1, 16, 64);
        accum9(acc + 18, q0); accum9(acc + 18, q1);
        float o = q0 + q1;                           // (4x,4y,8z)
        o += __shfl_xor(o, 1, 64);                   // x-oct
        o += __shfl_xor(o, 32, 64);                  // y-oct -> L3, replicated x16
        accum9(acc + 27, o);
        if (h == 0) oct0 = o; else oct1 = o;
    }
    #pragma unroll
    for (int j = 9;  j < 18; ++j) acc[j] *= 0.5f;    // undo x2 replication
    #pragma unroll
    for (int j = 18; j < 27; ++j) acc[j] *= 0.25f;   // x4
    #pragma unroll
    for (int j = 27; j < 36; ++j) acc[j] *= 0.0625f; // x16

    if ((l & 57) == 0) {              // lanes 0,2,4,6: one writer per 16-lane group
        int x3 = (l >> 1) & 3, y3 = wv & 3;
        m3[(zb * 2 + 0) * 16 + y3 * 4 + x3] = oct0;
        m3[(zb * 2 + 1) * 16 + y3 * 4 + x3] = oct1;
    }
    __syncthreads();

    // L4 (2x2x2 of L3) + L5, serial on t==0 (~200 cycles), stats stored direct.
    if (t == 0) {
        float a45[18];
        #pragma unroll
        for (int q = 0; q < 18; ++q) a45[q] = 0.0f;
        float s5 = 0.0f;
        #pragma unroll
        for (int c = 0; c < 8; ++c) {
            int x4 = c & 1, y4 = (c >> 1) & 1, z4 = c >> 2;
            float s = 0.0f;
            #pragma unroll
            for (int dz = 0; dz < 2; ++dz)
                #pragma unroll
                for (int dy = 0; dy < 2; ++dy)
                    #pragma unroll
                    for (int dx = 0; dx < 2; ++dx)
                        s += m3[(2 * z4 + dz) * 16 + (2 * y4 + dy) * 4 + (2 * x4 + dx)];
            accum9(a45, s);
            s5 += s;
        }
        accum9(a45 + 9, s5);
        #pragma unroll
        for (int q = 0; q < 18; ++q)
            part[((size_t)ch * 54 + 36 + q) * 64 + blk] = a45[q];
    }

    block_reduce<36>(acc, red, t);
    if (t < 36) {
        float s = 0.0f;
        #pragma unroll
        for (int w2 = 0; w2 < 8; ++w2) s += red[w2 * 36 + t];
        part[((size_t)ch * 54 + t) * 64 + blk] = s;
    }
}

// One wave per channel: reduce 64 block-partials per stat, then the finale.
__global__ __launch_bounds__(64) void k_fin(const float* __restrict__ part,
                                            const int* __restrict__ bounds,
                                            float* __restrict__ out) {
    __shared__ float sst[54];
    const int t  = threadIdx.x;       // 0..63 = block index within channel
    const int ch = blockIdx.x;

    #pragma unroll
    for (int j = 0; j < 54; ++j) {
        float v = part[((size_t)ch * 54 + j) * 64 + t];
        v += __shfl_down(v, 32, 64);
        v += __shfl_down(v, 16, 64);
        v += __shfl_down(v, 8, 64);
        v += __shfl_down(v, 4, 64);
        v += __shfl_down(v, 2, 64);
        v += __shfl_down(v, 1, 64);
        if (t == 0) sst[j] = v;
    }
    __syncthreads();

    // ---- finale: least-squares slope, double precision, 8 outputs ----
    if (t < 8) {
        int k = bounds[t];
        const double LN2 = 0.6931471805599453094;
        double b  = (double)sst[3];          // S_1 at level 0 == total sum
        double lb = log(b);
        double num = 0.0;
        #pragma unroll
        for (int s = 0; s < 6; ++s) {
            const float* st = sst + s * 9;
            double p;
            if (k == 1) p = ((double)st[8] - lb * (double)st[3]) / b;
            else        p = log((double)st[k + 2]) - (double)k * lb;
            num += (6.0 * s - 15.0) * LN2 * p;   // n*q_s - qs
        }
        double den = 105.0 * LN2 * LN2;          // n*q2s - qs^2
        double aa  = (k == 1) ? 1.0 : 1.0 / (double)(k - 1);
        out[ch * 8 + t] = (float)(aa * num / den);
    }
}

extern "C" void kernel_launch(void* const* d_in, const int* in_sizes, int n_in,
                              void* d_out, int out_size, void* d_ws, size_t ws_size,
                              hipStream_t stream) {
    const float* img    = (const float*)d_in[0];
    const int*   bounds = (const int*)d_in[1];
    float*       out    = (float*)d_out;
    float*       ws     = (float*)d_ws;

    // ws layout (floats): part[6*54*64 = 20736] @0. No l3map, no flags.
    float* part = ws;

    k_main<<<dim3(64, 6), 512, 0, stream>>>(img, part);
    k_fin<<<6, 64, 0, stream>>>(part, bounds, out);
}

// Round 10
// 110.860 us; speedup vs baseline: 1.6474x; 1.2471x over previous
//
#include <hip/hip_runtime.h>

#define CHVOL (128*128*128)

// 9 stats: [S_-2, S_-1, S_0(count), S_1, S_2, S_3, S_4, S_5, T=sum x*ln x]
__device__ __forceinline__ void accum9(float* a, float x) {
    bool nz = (x != 0.0f);
    float u = nz ? __builtin_amdgcn_rcpf(x) : 0.0f;
    float l = nz ? __logf(x) : 0.0f;
    float x2 = x * x;
    float x4 = x2 * x2;
    a[0] = fmaf(u, u, a[0]);
    a[1] += u;
    a[2] += nz ? 1.0f : 0.0f;
    a[3] += x;
    a[4] += x2;
    a[5] = fmaf(x2, x, a[5]);
    a[6] += x4;
    a[7] = fmaf(x4, x, a[7]);
    a[8] = fmaf(x, l, a[8]);
}

// In-wave reduce of NS stats; lane 0 of each wave holds the wave total.
template<int NS>
__device__ __forceinline__ void wave_reduce(float* acc) {
    #pragma unroll
    for (int s = 0; s < NS; ++s) {
        float v = acc[s];
        v += __shfl_down(v, 32, 64);
        v += __shfl_down(v, 16, 64);
        v += __shfl_down(v, 8, 64);
        v += __shfl_down(v, 4, 64);
        v += __shfl_down(v, 2, 64);
        v += __shfl_down(v, 1, 64);
        acc[s] = v;
    }
}

template<int NS>
__device__ __forceinline__ void block_reduce(float* acc, float* red, int t) {
    #pragma unroll
    for (int s = 0; s < NS; ++s) {
        float v = acc[s];
        v += __shfl_down(v, 32, 64);
        v += __shfl_down(v, 16, 64);
        v += __shfl_down(v, 8, 64);
        v += __shfl_down(v, 4, 64);
        v += __shfl_down(v, 2, 64);
        v += __shfl_down(v, 1, 64);
        if ((t & 63) == 0) red[(t >> 6) * NS + s] = v;
    }
    __syncthreads();
}

// ===== PRODUCER: identical to round 0/6 (proven, bit-exact, <42.5 us) =====
// Region = 128(x) x 8(y) x 8(z); levels 0-3 in-block; 8-deep prefetch.
__global__ __launch_bounds__(256) void k_main(const float* __restrict__ img,
                                              float* __restrict__ part,
                                              float* __restrict__ l3map) {
    __shared__ float zm[256];        // [w4][z''2][x32]
    __shared__ float red[36 * 4];

    const int t  = threadIdx.x;
    const int l  = t & 63, w = t >> 6;
    const int r  = blockIdx.x;        // 0..255
    const int ch = blockIdx.y;        // 0..5
    const int ry = r & 15, rz = r >> 4;
    const float* base = img + (size_t)ch * CHVOL + rz * (8 * 16384) + ry * (8 * 128);

    float acc[36];
    #pragma unroll
    for (int j = 0; j < 36; ++j) acc[j] = 0.0f;

    const int x5 = l & 31;
    const int y  = ((l >> 5) & 1) | (w << 1);   // y in [0,8)
    const float* tbase = base + y * 128 + x5 * 4;

    float4 v[8];
    #pragma unroll
    for (int i = 0; i < 8; ++i) v[i] = *(const float4*)(tbase + i * 16384);

    float d0 = 0.0f, d1 = 0.0f;
    float ca = 0.0f, cb = 0.0f;
    #pragma unroll
    for (int i = 0; i < 8; ++i) {
        accum9(acc, v[i].x); accum9(acc, v[i].y); accum9(acc, v[i].z); accum9(acc, v[i].w);
        float a = v[i].x + v[i].y, b = v[i].z + v[i].w;
        a += __shfl_xor(a, 32, 64);
        b += __shfl_xor(b, 32, 64);
        if ((i & 1) == 0) { ca = a; cb = b; }
        else {
            float A = ca + a, B = cb + b;
            accum9(acc + 9, A); accum9(acc + 9, B);
            if (i < 4) d0 += A + B; else d1 += A + B;
        }
    }
    #pragma unroll
    for (int j = 9; j < 18; ++j) acc[j] *= 0.5f;

    if ((l >> 5) == 0) {
        zm[w * 64 + x5]      = d0;
        zm[w * 64 + 32 + x5] = d1;
    }
    __syncthreads();

    if (t < 128) {
        int x = t & 31, zpp = (t >> 5) & 1, ypp = t >> 6;
        float s = zm[(2 * ypp) * 64 + zpp * 32 + x] + zm[(2 * ypp + 1) * 64 + zpp * 32 + x];
        accum9(acc + 18, s);
    }
    if (t < 16) {
        float s = 0.0f;
        #pragma unroll
        for (int q = 0; q < 8; ++q)
            s += zm[q * 32 + 2 * t] + zm[q * 32 + 2 * t + 1];
        accum9(acc + 27, s);
        l3map[(size_t)ch * 4096 + rz * 256 + ry * 16 + t] = s;
    }

    block_reduce<36>(acc, red, t);
    if (t < 36)
        part[((size_t)ch * 36 + t) * 256 + r] =
            red[t] + red[36 + t] + red[72 + t] + red[108 + t];
}

// ===== CONSUMER: lean 512-thread, one block/channel, 2 syncs =====
// Waves 0-3: stream part (36 coalesced loads/thread) -> 36-stat reduce.
// Waves 4-7 CONCURRENTLY: gather all 512 L4 cells (2/thread, 16 float2
// loads) -> M4 + 9-stat reduce. All ~300 KB of loads in flight at once.
// Then L5 from LDS in wave 0, finale. No serialized phase chain.
__global__ __launch_bounds__(512) void k_fin(const float* __restrict__ part,
                                             const float* __restrict__ l3map,
                                             const int* __restrict__ bounds,
                                             float* __restrict__ out) {
    __shared__ float M4[512];
    __shared__ float redA[36 * 4];
    __shared__ float redB[9 * 4];
    __shared__ float sst[54];

    const int t  = threadIdx.x;
    const int ch = blockIdx.x;

    if (t < 256) {
        // ---- levels 0-3 from block partials (coalesced, 1 load/thread/stat)
        float acc[36];
        #pragma unroll
        for (int j = 0; j < 36; ++j)
            acc[j] = part[((size_t)ch * 36 + j) * 256 + t];
        wave_reduce<36>(acc);
        if ((t & 63) == 0) {
            #pragma unroll
            for (int s = 0; s < 36; ++s) redA[(t >> 6) * 36 + s] = acc[s];
        }
    } else {
        // ---- level 4: pool l3map 16^3 -> 8^3, two cells per thread
        const float2* L3 = (const float2*)(l3map + (size_t)ch * 4096);
        const int th = t - 256;
        float a9[9];
        #pragma unroll
        for (int j = 0; j < 9; ++j) a9[j] = 0.0f;
        #pragma unroll
        for (int i = 0; i < 2; ++i) {
            int c = th + i * 256;
            int x = c & 7, y = (c >> 3) & 7, z = c >> 6;
            const float2* p = L3 + z * 256 + y * 16 + x;   // f2 idx = 2z*128+2y*8+x
            float2 b0 = p[0], b1 = p[8], b2 = p[128], b3 = p[136];
            float s = (b0.x + b0.y) + (b1.x + b1.y) + (b2.x + b2.y) + (b3.x + b3.y);
            M4[c] = s;
            accum9(a9, s);
        }
        wave_reduce<9>(a9);
        if ((t & 63) == 0) {
            #pragma unroll
            for (int s = 0; s < 9; ++s) redB[((t >> 6) - 4) * 9 + s] = a9[s];
        }
    }
    __syncthreads();

    // ---- combine partials into sst (wave 0), L5 from M4 in-wave ----
    if (t < 36) sst[t] = redA[t] + redA[36 + t] + redA[72 + t] + redA[108 + t];
    if (t >= 36 && t < 45) {
        int s = t - 36;
        sst[36 + s] = redB[s] + redB[9 + s] + redB[18 + s] + redB[27 + s];
    }
    if (t < 64) {
        float c9[9];
        #pragma unroll
        for (int j = 0; j < 9; ++j) c9[j] = 0.0f;
        int x = t & 3, y = (t >> 2) & 3, z = t >> 4;
        const float2* p = (const float2*)M4 + z * 64 + y * 8 + x;  // 2z*32+2y*4+x
        float2 b0 = p[0], b1 = p[4], b2 = p[32], b3 = p[36];
        float s = (b0.x + b0.y) + (b1.x + b1.y) + (b2.x + b2.y) + (b3.x + b3.y);
        accum9(c9, s);
        wave_reduce<9>(c9);
        if (t == 0) {
            #pragma unroll
            for (int j = 0; j < 9; ++j) sst[45 + j] = c9[j];
        }
    }
    __syncthreads();

    // ---- finale: least-squares slope, double precision, 8 outputs ----
    if (t < 8) {
        int k = bounds[t];
        const double LN2 = 0.6931471805599453094;
        double b  = (double)sst[3];          // S_1 at level 0 == total sum
        double lb = log(b);
        double num = 0.0;
        #pragma unroll
        for (int s = 0; s < 6; ++s) {
            const float* st = sst + s * 9;
            double p;
            if (k == 1) p = ((double)st[8] - lb * (double)st[3]) / b;
            else        p = log((double)st[k + 2]) - (double)k * lb;
            num += (6.0 * s - 15.0) * LN2 * p;   // n*q_s - qs
        }
        double den = 105.0 * LN2 * LN2;          // n*q2s - qs^2
        double aa  = (k == 1) ? 1.0 : 1.0 / (double)(k - 1);
        out[ch * 8 + t] = (float)(aa * num / den);
    }
}

extern "C" void kernel_launch(void* const* d_in, const int* in_sizes, int n_in,
                              void* d_out, int out_size, void* d_ws, size_t ws_size,
                              hipStream_t stream) {
    const float* img    = (const float*)d_in[0];
    const int*   bounds = (const int*)d_in[1];
    float*       out    = (float*)d_out;
    float*       ws     = (float*)d_ws;

    // ws layout (floats): part[6*36*256=55296] @0, l3map[6*4096=24576] @55296.
    float* part  = ws;
    float* l3map = ws + 55296;

    k_main<<<dim3(256, 6), 256, 0, stream>>>(img, part, l3map);
    k_fin<<<6, 512, 0, stream>>>(part, l3map, bounds, out);
}